// Round 1
// baseline (191325.879 us; speedup 1.0000x reference)
//
#include <hip/hip_runtime.h>
#include <math.h>

// 3-layer LSTM (B=64, H=512, T=512, F=513) + FC(512)->ReLU->FC(513).
// Round 0: fp32 baseline, one kernel per (t, layer) => 1536 + 2 kernels.
// Block = 256 threads = 4 output channels (j) x 64 batch (b).
// Input/h staged in LDS (padded stride 129 -> conflict-free reads).
// Weight rows accessed through readfirstlane-uniform pointers (SMEM loads).

#define KT 128
#define BB 64     // batch
#define HH 512    // hidden
#define TT 512    // timesteps

__device__ __forceinline__ float sigf(float x) { return 1.0f / (1.0f + expf(-x)); }

template <int DIN, bool STRIDED>
__global__ __launch_bounds__(256) void lstm_step_k(
    const float* __restrict__ xin,   // STRIDED: x + t, elem [b][k] at b*DIN*TT + k*TT
                                     // else: [64][DIN] row-major
    const float* __restrict__ h_in,  // [64][512]
    const float* __restrict__ c_in,  // [64][512]
    float* __restrict__ h_out,       // [64][512]
    float* __restrict__ c_out,       // [64][512]
    const float* __restrict__ Wih,   // [2048][DIN]
    const float* __restrict__ Whh,   // [2048][512]
    const float* __restrict__ bih,   // [2048]
    const float* __restrict__ bhh)   // [2048]
{
    __shared__ float xs[BB][KT + 1];

    const int tid = (int)threadIdx.x;
    const int b   = tid & 63;
    const int jl  = tid >> 6;                  // 0..3, wave-uniform
    const int j   = (int)blockIdx.x * 4 + jl;  // 0..511
    const int ju  = __builtin_amdgcn_readfirstlane(j);

    const float* __restrict__ w0 = Wih + (size_t)(ju       ) * DIN;
    const float* __restrict__ w1 = Wih + (size_t)(ju +  512) * DIN;
    const float* __restrict__ w2 = Wih + (size_t)(ju + 1024) * DIN;
    const float* __restrict__ w3 = Wih + (size_t)(ju + 1536) * DIN;

    float a0 = 0.f, a1 = 0.f, a2 = 0.f, a3 = 0.f;

    // ---------- phase A: x @ Wih^T ----------
    constexpr int KFULL = (DIN / KT) * KT;
    for (int k0 = 0; k0 < KFULL; k0 += KT) {
        __syncthreads();
#pragma unroll
        for (int r = 0; r < (BB * KT) / 256; ++r) {
            int idx = tid + r * 256;
            int bb = idx / KT, kk = idx % KT;
            xs[bb][kk] = STRIDED ? xin[(size_t)bb * DIN * TT + (size_t)(k0 + kk) * TT]
                                 : xin[(size_t)bb * DIN + (k0 + kk)];
        }
        __syncthreads();
#pragma unroll 32
        for (int k = 0; k < KT; ++k) {
            float xv = xs[b][k];
            a0 = fmaf(w0[k0 + k], xv, a0);
            a1 = fmaf(w1[k0 + k], xv, a1);
            a2 = fmaf(w2[k0 + k], xv, a2);
            a3 = fmaf(w3[k0 + k], xv, a3);
        }
    }
    if (DIN > KFULL) {  // ragged tail (DIN=513 -> 1 column)
        constexpr int REM = DIN - KFULL;
        __syncthreads();
        for (int idx = tid; idx < BB * REM; idx += 256) {
            int bb = idx / REM, kk = idx % REM;
            xs[bb][kk] = STRIDED ? xin[(size_t)bb * DIN * TT + (size_t)(KFULL + kk) * TT]
                                 : xin[(size_t)bb * DIN + (KFULL + kk)];
        }
        __syncthreads();
        for (int k = 0; k < REM; ++k) {
            float xv = xs[b][k];
            a0 = fmaf(w0[KFULL + k], xv, a0);
            a1 = fmaf(w1[KFULL + k], xv, a1);
            a2 = fmaf(w2[KFULL + k], xv, a2);
            a3 = fmaf(w3[KFULL + k], xv, a3);
        }
    }

    // ---------- phase B: h @ Whh^T ----------
    const float* __restrict__ v0 = Whh + (size_t)(ju       ) * HH;
    const float* __restrict__ v1 = Whh + (size_t)(ju +  512) * HH;
    const float* __restrict__ v2 = Whh + (size_t)(ju + 1024) * HH;
    const float* __restrict__ v3 = Whh + (size_t)(ju + 1536) * HH;

    for (int k0 = 0; k0 < HH; k0 += KT) {
        __syncthreads();
#pragma unroll
        for (int r = 0; r < (BB * KT) / 256; ++r) {
            int idx = tid + r * 256;
            int bb = idx / KT, kk = idx % KT;
            xs[bb][kk] = h_in[(size_t)bb * HH + (k0 + kk)];
        }
        __syncthreads();
#pragma unroll 32
        for (int k = 0; k < KT; ++k) {
            float xv = xs[b][k];
            a0 = fmaf(v0[k0 + k], xv, a0);
            a1 = fmaf(v1[k0 + k], xv, a1);
            a2 = fmaf(v2[k0 + k], xv, a2);
            a3 = fmaf(v3[k0 + k], xv, a3);
        }
    }

    // ---------- gates + pointwise ----------
    a0 += bih[j]        + bhh[j];
    a1 += bih[j +  512] + bhh[j +  512];
    a2 += bih[j + 1024] + bhh[j + 1024];
    a3 += bih[j + 1536] + bhh[j + 1536];

    float i_ = sigf(a0);
    float f_ = sigf(a1);
    float g_ = tanhf(a2);
    float o_ = sigf(a3);

    float cprev = c_in[(size_t)b * HH + j];
    float cn = f_ * cprev + i_ * g_;
    float hn = o_ * tanhf(cn);

    h_out[(size_t)b * HH + j] = hn;
    c_out[(size_t)b * HH + j] = cn;
}

template <bool RELU>
__global__ __launch_bounds__(256) void linear_k(
    const float* __restrict__ in,    // [64][512]
    const float* __restrict__ W,     // [N][512]
    const float* __restrict__ bias,  // [N]
    float* __restrict__ out,         // [64][N]
    int N)
{
    __shared__ float xs[BB][KT + 1];
    const int tid = (int)threadIdx.x;
    const int b   = tid & 63;
    const int nl  = tid >> 6;
    const int n   = (int)blockIdx.x * 4 + nl;
    const int nc  = (n < N) ? n : (N - 1);
    const int nu  = __builtin_amdgcn_readfirstlane(nc);
    const float* __restrict__ w = W + (size_t)nu * HH;

    float a = 0.f;
    for (int k0 = 0; k0 < HH; k0 += KT) {
        __syncthreads();
#pragma unroll
        for (int r = 0; r < (BB * KT) / 256; ++r) {
            int idx = tid + r * 256;
            int bb = idx / KT, kk = idx % KT;
            xs[bb][kk] = in[(size_t)bb * HH + (k0 + kk)];
        }
        __syncthreads();
#pragma unroll 32
        for (int k = 0; k < KT; ++k)
            a = fmaf(w[k0 + k], xs[b][k], a);
    }
    if (n < N) {
        a += bias[n];
        if (RELU) a = fmaxf(a, 0.f);
        out[(size_t)b * N + n] = a;
    }
}

extern "C" void kernel_launch(void* const* d_in, const int* in_sizes, int n_in,
                              void* d_out, int out_size, void* d_ws, size_t ws_size,
                              hipStream_t stream)
{
    const float* x     = (const float*)d_in[0];
    const float* Wih1  = (const float*)d_in[1];
    const float* Whh1  = (const float*)d_in[2];
    const float* bih1  = (const float*)d_in[3];
    const float* bhh1  = (const float*)d_in[4];
    const float* Wih2  = (const float*)d_in[5];
    const float* Whh2  = (const float*)d_in[6];
    const float* bih2  = (const float*)d_in[7];
    const float* bhh2  = (const float*)d_in[8];
    const float* Wih3  = (const float*)d_in[9];
    const float* Whh3  = (const float*)d_in[10];
    const float* bih3  = (const float*)d_in[11];
    const float* bhh3  = (const float*)d_in[12];
    const float* fc1_w = (const float*)d_in[13];
    const float* fc1_b = (const float*)d_in[14];
    const float* fc2_w = (const float*)d_in[15];
    const float* fc2_b = (const float*)d_in[16];

    float* ws = (float*)d_ws;
    const size_t SB = (size_t)BB * HH;  // 32768 floats per state
    float* hbuf = ws;                    // [2][3][SB]
    float* cbuf = ws + 6 * SB;           // [2][3][SB]
    float* hid  = ws + 12 * SB;          // [64][512]
    const size_t need_bytes = (13 * SB) * sizeof(float);
    if (ws_size < need_bytes) return;    // defensive: leaves output wrong but no corruption

    auto hp = [&](int p, int l) { return hbuf + ((size_t)p * 3 + l) * SB; };
    auto cp = [&](int p, int l) { return cbuf + ((size_t)p * 3 + l) * SB; };

    hipMemcpyAsync(hp(0, 0), d_in[17], SB * 4, hipMemcpyDeviceToDevice, stream);
    hipMemcpyAsync(cp(0, 0), d_in[18], SB * 4, hipMemcpyDeviceToDevice, stream);
    hipMemcpyAsync(hp(0, 1), d_in[19], SB * 4, hipMemcpyDeviceToDevice, stream);
    hipMemcpyAsync(cp(0, 1), d_in[20], SB * 4, hipMemcpyDeviceToDevice, stream);
    hipMemcpyAsync(hp(0, 2), d_in[21], SB * 4, hipMemcpyDeviceToDevice, stream);
    hipMemcpyAsync(cp(0, 2), d_in[22], SB * 4, hipMemcpyDeviceToDevice, stream);

    int p = 0;
    for (int t = 0; t < TT; ++t) {
        const int q = 1 - p;
        lstm_step_k<513, true ><<<128, 256, 0, stream>>>(
            x + t, hp(p, 0), cp(p, 0), hp(q, 0), cp(q, 0), Wih1, Whh1, bih1, bhh1);
        lstm_step_k<512, false><<<128, 256, 0, stream>>>(
            hp(q, 0), hp(p, 1), cp(p, 1), hp(q, 1), cp(q, 1), Wih2, Whh2, bih2, bhh2);
        lstm_step_k<512, false><<<128, 256, 0, stream>>>(
            hp(q, 1), hp(p, 2), cp(p, 2), hp(q, 2), cp(q, 2), Wih3, Whh3, bih3, bhh3);
        p = q;
    }

    linear_k<true ><<<128, 256, 0, stream>>>(hp(p, 2), fc1_w, fc1_b, hid, 512);
    linear_k<false><<<129, 256, 0, stream>>>(hid, fc2_w, fc2_b, (float*)d_out, 513);
}

// Round 2
// 21205.069 us; speedup vs baseline: 9.0226x; 9.0226x over previous
//
#include <hip/hip_runtime.h>
#include <math.h>

// 3-layer LSTM (B=64, H=512, T=512, F=513) + FC(512)->ReLU->FC(513). fp32.
// R1: full-GPU per-step kernels.
//  - Layer-1 input GEMM batched over 64-t chunks (gx = Wih1@x + bias), x read
//    coalesced along t (its contiguous axis).
//  - Recurrent kernels: 256 blocks x 512 thr; block = 2 units (8 gate rows);
//    8 waves k-split K; LDS partial reduce; weights via wave-uniform scalar
//    loads; h/c stored transposed [unit][b] so lane=b loads are coalesced.

#define BB 64
#define HH 512
#define TT 512
#define FF 513
#define GG 2048   // 4*HH gate rows
#define TC 64     // t-chunk for gx

__device__ __forceinline__ float sigf(float x) { return 1.0f / (1.0f + expf(-x)); }

// ---------------- init transposes ----------------
__global__ __launch_bounds__(256) void transpose_states(
    const float* __restrict__ s0, const float* __restrict__ s1,
    const float* __restrict__ s2, const float* __restrict__ s3,
    const float* __restrict__ s4, const float* __restrict__ s5,
    float* __restrict__ d0, float* __restrict__ d1,
    float* __restrict__ d2, float* __restrict__ d3,
    float* __restrict__ d4, float* __restrict__ d5)
{
    int idx = blockIdx.x * 256 + threadIdx.x;          // 6 * 32768
    int arr = idx >> 15, e = idx & 32767;
    int b = e >> 9, u = e & 511;                        // read [b][u] coalesced
    const float* s = arr == 0 ? s0 : arr == 1 ? s1 : arr == 2 ? s2
                   : arr == 3 ? s3 : arr == 4 ? s4 : s5;
    float* d = arr == 0 ? d0 : arr == 1 ? d1 : arr == 2 ? d2
             : arr == 3 ? d3 : arr == 4 ? d4 : d5;
    d[u * 64 + b] = s[e];
}

__global__ __launch_bounds__(256) void transpose_wih1(
    const float* __restrict__ Wih1, float* __restrict__ WihT)  // [GG][FF] -> [FF][GG]
{
    int idx = blockIdx.x * 256 + threadIdx.x;
    if (idx >= GG * FF) return;
    int j = idx / FF, f = idx - j * FF;                 // read coalesced
    WihT[(size_t)f * GG + j] = Wih1[idx];
}

// ---------------- batched layer-1 input GEMM ----------------
// gx[j][b][tl] = bih1[j] + bhh1[j] + sum_f Wih1[j][f] * x[b][f][t0+tl]
// grid: 2048 blocks = 16 bg x 128 jg; block 256 thr = 4 waves (wave => one b),
// lanes = tl (0..63); 16 j-accumulators per wave.
__global__ __launch_bounds__(256) void gx_batch(
    const float* __restrict__ x,     // [64][513][512]
    const float* __restrict__ WihT,  // [513][2048]
    const float* __restrict__ bih1, const float* __restrict__ bhh1,
    float* __restrict__ gx,          // [2048][64][TC]
    int t0)
{
    const int lane = threadIdx.x & 63;
    const int wv = __builtin_amdgcn_readfirstlane(threadIdx.x >> 6);
    const int bg = blockIdx.x >> 7;      // 0..15
    const int jg = blockIdx.x & 127;     // 0..127
    const int b = bg * 4 + wv;
    const int j0 = jg * 16;

    float acc[16];
#pragma unroll
    for (int i = 0; i < 16; ++i) acc[i] = 0.f;

    const float* xp = x + (size_t)b * FF * TT + t0 + lane;
    for (int f = 0; f < FF; ++f) {
        float xv = xp[(size_t)f * TT];                   // coalesced along t
        const float* wr = WihT + (size_t)f * GG + j0;    // wave-uniform
#pragma unroll
        for (int jj = 0; jj < 16; ++jj) acc[jj] = fmaf(wr[jj], xv, acc[jj]);
    }
#pragma unroll
    for (int jj = 0; jj < 16; ++jj) {
        int j = j0 + jj;
        gx[((size_t)j * 64 + b) * TC + lane] = acc[jj] + bih1[j] + bhh1[j];
    }
}

// ---------------- recurrent layer-step ----------------
// gates[j][b] = base + sum_k Wa[j][k]*ha[k][b] (+ sum_k Wb[j][k]*hb[k][b])
// base = gx[j][b][tl] (L1) or bih[j]+bhh[j] (L2/L3).
// 256 blocks x 512 thr; block owns units {u0,u0+1} => rows j = u0+(jj&1)+(jj>>1)*512.
template <bool HAS2>
__global__ __launch_bounds__(512) void lstm_step(
    const float* __restrict__ gx, int tl,
    const float* __restrict__ Wa, const float* __restrict__ ha,
    const float* __restrict__ Wb, const float* __restrict__ hb,
    const float* __restrict__ bih, const float* __restrict__ bhh,
    float* __restrict__ c,          // cT [512][64], in-place
    float* __restrict__ h_out)      // hT [512][64]
{
    __shared__ float part[8][8][64];
    __shared__ float gred[8][64];
    const int tid = threadIdx.x;
    const int lane = tid & 63;
    const int wv = __builtin_amdgcn_readfirstlane(tid >> 6);
    const int u0 = blockIdx.x * 2;

    float acc[8];
#pragma unroll
    for (int i = 0; i < 8; ++i) acc[i] = 0.f;

    const float* W; const float* hs; int kb, ks;
    if (HAS2) {
        if (wv < 4) { W = Wa; hs = ha; kb = wv * 128; }
        else        { W = Wb; hs = hb; kb = (wv - 4) * 128; }
        ks = 128;
    } else {
        W = Wa; hs = ha; kb = wv * 64; ks = 64;
    }

    for (int kc = kb; kc < kb + ks; kc += 16) {
        float hv[16];
#pragma unroll
        for (int i = 0; i < 16; ++i) hv[i] = hs[(size_t)(kc + i) * 64 + lane];
#pragma unroll
        for (int jj = 0; jj < 8; ++jj) {
            const int j = u0 + (jj & 1) + (jj >> 1) * 512;
            const float* wr = W + (size_t)j * HH + kc;   // wave-uniform -> s_load
#pragma unroll
            for (int i = 0; i < 16; ++i) acc[jj] = fmaf(wr[i], hv[i], acc[jj]);
        }
    }
#pragma unroll
    for (int jj = 0; jj < 8; ++jj) part[wv][jj][lane] = acc[jj];
    __syncthreads();

    {   // reduce: thread (jj=wv, b=lane)
        const int jj = wv, b = lane;
        const int j = u0 + (jj & 1) + (jj >> 1) * 512;
        float s = 0.f;
#pragma unroll
        for (int w = 0; w < 8; ++w) s += part[w][jj][b];
        s += HAS2 ? (bih[j] + bhh[j]) : gx[((size_t)j * 64 + b) * TC + tl];
        gred[jj][b] = s;
    }
    __syncthreads();

    if (tid < 128) {
        const int u = tid >> 6, b = lane;
        const int uu = u0 + u;
        float gi = gred[0 + u][b];
        float gf = gred[2 + u][b];
        float gg = gred[4 + u][b];
        float go = gred[6 + u][b];
        float cold = c[(size_t)uu * 64 + b];
        float cn = sigf(gf) * cold + sigf(gi) * tanhf(gg);
        float hn = sigf(go) * tanhf(cn);
        c[(size_t)uu * 64 + b] = cn;
        h_out[(size_t)uu * 64 + b] = hn;
    }
}

// ---------------- final FCs ----------------
template <bool RELU, bool TOUT>
__global__ __launch_bounds__(256) void linear_T(
    const float* __restrict__ inT,   // [K][64]
    const float* __restrict__ W,     // [N][K]
    const float* __restrict__ bias,
    float* __restrict__ out,         // TOUT: [N][64] else [64][N]
    int N, int K)
{
    const int lane = threadIdx.x & 63;
    const int nl = __builtin_amdgcn_readfirstlane(threadIdx.x >> 6);
    const int n = blockIdx.x * 4 + nl;
    if (n >= N) return;
    float acc = 0.f;
    for (int k = 0; k < K; k += 8) {
        float hv[8];
#pragma unroll
        for (int i = 0; i < 8; ++i) hv[i] = inT[(size_t)(k + i) * 64 + lane];
        const float* wr = W + (size_t)n * K + k;
#pragma unroll
        for (int i = 0; i < 8; ++i) acc = fmaf(wr[i], hv[i], acc);
    }
    acc += bias[n];
    if (RELU) acc = fmaxf(acc, 0.f);
    if (TOUT) out[(size_t)n * 64 + lane] = acc;
    else      out[(size_t)lane * N + n] = acc;
}

extern "C" void kernel_launch(void* const* d_in, const int* in_sizes, int n_in,
                              void* d_out, int out_size, void* d_ws, size_t ws_size,
                              hipStream_t stream)
{
    const float* x     = (const float*)d_in[0];
    const float* Wih1  = (const float*)d_in[1];
    const float* Whh1  = (const float*)d_in[2];
    const float* bih1  = (const float*)d_in[3];
    const float* bhh1  = (const float*)d_in[4];
    const float* Wih2  = (const float*)d_in[5];
    const float* Whh2  = (const float*)d_in[6];
    const float* bih2  = (const float*)d_in[7];
    const float* bhh2  = (const float*)d_in[8];
    const float* Wih3  = (const float*)d_in[9];
    const float* Whh3  = (const float*)d_in[10];
    const float* bih3  = (const float*)d_in[11];
    const float* bhh3  = (const float*)d_in[12];
    const float* fc1_w = (const float*)d_in[13];
    const float* fc1_b = (const float*)d_in[14];
    const float* fc2_w = (const float*)d_in[15];
    const float* fc2_b = (const float*)d_in[16];

    float* ws = (float*)d_ws;
    const size_t SB = (size_t)HH * BB;   // 32768 floats, transposed state
    // layout (floats): hT[2][3][SB] | cT[3][SB] | hidT[SB] | WihT[FF*GG] | gx[GG*BB*TC]
    float* hT   = ws;
    float* cT   = hT + 6 * SB;
    float* hidT = cT + 3 * SB;
    float* WihT = hidT + SB;
    float* gx   = WihT + (size_t)FF * GG;
    const size_t need = (size_t)(10 * SB) + (size_t)FF * GG + (size_t)GG * BB * TC;
    if (ws_size < need * sizeof(float)) return;

    auto hp = [&](int p, int l) { return hT + ((size_t)p * 3 + l) * SB; };
    auto cp = [&](int l) { return cT + (size_t)l * SB; };

    transpose_states<<<768, 256, 0, stream>>>(
        (const float*)d_in[17], (const float*)d_in[18], (const float*)d_in[19],
        (const float*)d_in[20], (const float*)d_in[21], (const float*)d_in[22],
        hp(0, 0), cp(0), hp(0, 1), cp(1), hp(0, 2), cp(2));
    transpose_wih1<<<(GG * FF + 255) / 256, 256, 0, stream>>>(Wih1, WihT);

    int p = 0;
    for (int t = 0; t < TT; ++t) {
        if ((t & (TC - 1)) == 0)
            gx_batch<<<2048, 256, 0, stream>>>(x, WihT, bih1, bhh1, gx, t);
        const int q = 1 - p;
        const int tl = t & (TC - 1);
        lstm_step<false><<<256, 512, 0, stream>>>(
            gx, tl, Whh1, hp(p, 0), nullptr, nullptr, nullptr, nullptr,
            cp(0), hp(q, 0));
        lstm_step<true><<<256, 512, 0, stream>>>(
            nullptr, 0, Wih2, hp(q, 0), Whh2, hp(p, 1), bih2, bhh2,
            cp(1), hp(q, 1));
        lstm_step<true><<<256, 512, 0, stream>>>(
            nullptr, 0, Wih3, hp(q, 1), Whh3, hp(p, 2), bih3, bhh3,
            cp(2), hp(q, 2));
        p = q;
    }

    linear_T<true,  true ><<<128, 256, 0, stream>>>(hp(p, 2), fc1_w, fc1_b, hidT, 512, 512);
    linear_T<false, false><<<129, 256, 0, stream>>>(hidT, fc2_w, fc2_b, (float*)d_out, 513, 512);
}

// Round 3
// 17664.537 us; speedup vs baseline: 10.8311x; 1.2004x over previous
//
#include <hip/hip_runtime.h>
#include <math.h>

// 3-layer LSTM (B=64, H=512, T=512, F=513) + FC(512)->ReLU->FC(513). fp32.
// R2: diagonal-wavefront pipeline. One kernel per super-step s computes
//   L1@t=s, L2@t=s-1, L3@t=s-2 on disjoint block sets (768 blocks x 256 thr,
//   3 blocks/CU). x is pre-transposed per 64-t chunk into a ring (xT[t][f][b])
//   so L1 fuses the input GEMM into its K-loop (no separate gx GEMM).
// h ring buffers with slot parity (t+1)&1; c in-place (block-owned rows).

#define BB 64
#define HH 512
#define TT 512
#define FF 513
#define SB (HH * BB)            // 32768 floats per state
#define XCH (64 * FF * BB)      // x-ring chunk: 2,101,248 floats

__device__ __forceinline__ float sigf(float x) { return 1.0f / (1.0f + expf(-x)); }

// ---------------- init state transpose: [64][512] -> [512][64] ----------------
__global__ __launch_bounds__(256) void transpose_states(
    const float* __restrict__ s0, const float* __restrict__ s1,
    const float* __restrict__ s2, const float* __restrict__ s3,
    const float* __restrict__ s4, const float* __restrict__ s5,
    float* __restrict__ d0, float* __restrict__ d1,
    float* __restrict__ d2, float* __restrict__ d3,
    float* __restrict__ d4, float* __restrict__ d5)
{
    int idx = blockIdx.x * 256 + threadIdx.x;          // 6 * 32768
    int arr = idx >> 15, e = idx & 32767;
    int b = e >> 9, u = e & 511;
    const float* s = arr == 0 ? s0 : arr == 1 ? s1 : arr == 2 ? s2
                   : arr == 3 ? s3 : arr == 4 ? s4 : s5;
    float* d = arr == 0 ? d0 : arr == 1 ? d1 : arr == 2 ? d2
             : arr == 3 ? d3 : arr == 4 ? d4 : d5;
    d[u * 64 + b] = s[e];
}

// ---------------- x chunk transpose: x[64][513][512] -> ring[64t][513][64b] ----
__global__ __launch_bounds__(256) void transpose_xchunk(
    const float* __restrict__ x, float* __restrict__ xring, int c)
{
    __shared__ float tile[64][65];
    const int f  = (int)blockIdx.x;        // 0..512
    const int t0 = c * 64;
    const int tid = (int)threadIdx.x;
    float* dst = xring + (size_t)(c & 1) * XCH;
#pragma unroll
    for (int p = 0; p < 16; ++p) {
        int idx = p * 256 + tid;
        int b = idx >> 6, tt = idx & 63;
        tile[b][tt] = x[(size_t)b * FF * TT + (size_t)f * TT + t0 + tt];  // coalesced in t
    }
    __syncthreads();
#pragma unroll
    for (int p = 0; p < 16; ++p) {
        int idx = p * 256 + tid;
        int tt = idx >> 6, b = idx & 63;
        dst[(size_t)tt * (FF * BB) + (size_t)f * BB + b] = tile[b][tt];   // coalesced in b
    }
}

// ---------------- diagonal super-step ----------------
// 768 blocks: layer = bid>>8 (0..2), unit-block = bid&255 -> units {u0,u0+1}.
// Wave wv takes K-quarter [wv*128, wv*128+128) of both phases; LDS partial reduce.
__global__ __launch_bounds__(256, 3) void lstm_diag(
    int s,
    const float* __restrict__ xring,
    const float* __restrict__ Wih1, const float* __restrict__ Whh1,
    const float* __restrict__ bih1, const float* __restrict__ bhh1,
    const float* __restrict__ Wih2, const float* __restrict__ Whh2,
    const float* __restrict__ bih2, const float* __restrict__ bhh2,
    const float* __restrict__ Wih3, const float* __restrict__ Whh3,
    const float* __restrict__ bih3, const float* __restrict__ bhh3,
    float* __restrict__ Hst,   // [3 layers][2 slots][512][64]
    float* __restrict__ Cst)   // [3 layers][512][64]
{
    const int layer = (int)blockIdx.x >> 8;
    const int t = s - layer;
    if (t < 0 || t >= TT) return;
    const int ublk = (int)blockIdx.x & 255;
    const int u0 = __builtin_amdgcn_readfirstlane(ublk * 2);
    const int tid = (int)threadIdx.x;
    const int lane = tid & 63;
    const int wv = __builtin_amdgcn_readfirstlane(tid >> 6);

    const float* inA; const float* WA; int ldA;
    const float* WB; const float* bihp; const float* bhhp;
    if (layer == 0) {
        inA = xring + (size_t)((t >> 6) & 1) * XCH + (size_t)(t & 63) * (FF * BB);
        WA = Wih1; ldA = FF; WB = Whh1; bihp = bih1; bhhp = bhh1;
    } else if (layer == 1) {
        inA = Hst + (size_t)(0 * 2 + ((t + 1) & 1)) * SB;   // h1 output of step t
        WA = Wih2; ldA = HH; WB = Whh2; bihp = bih2; bhhp = bhh2;
    } else {
        inA = Hst + (size_t)(1 * 2 + ((t + 1) & 1)) * SB;   // h2 output of step t
        WA = Wih3; ldA = HH; WB = Whh3; bihp = bih3; bhhp = bhh3;
    }
    const float* inB = Hst + (size_t)(layer * 2 + (t & 1)) * SB;        // own h state
    float* hout      = Hst + (size_t)(layer * 2 + ((t + 1) & 1)) * SB;
    float* cst       = Cst + (size_t)layer * SB;

    int jr[8];
#pragma unroll
    for (int rr = 0; rr < 8; ++rr) jr[rr] = (rr >> 1) * HH + u0 + (rr & 1);

    float acc[8];
#pragma unroll
    for (int rr = 0; rr < 8; ++rr) acc[rr] = 0.f;

    const int k0 = wv * 128;

    // ---- phase A: upstream input (x for L1, h_{l-1} for L2/L3) ----
    {
        const float* wr[8];
#pragma unroll
        for (int rr = 0; rr < 8; ++rr) wr[rr] = WA + (size_t)jr[rr] * ldA + k0;
        const float* ip = inA + (size_t)k0 * BB + lane;
        for (int k = 0; k < 128; k += 8) {
            float hv[8];
#pragma unroll
            for (int i = 0; i < 8; ++i) hv[i] = ip[(size_t)(k + i) * BB];
#pragma unroll
            for (int rr = 0; rr < 8; ++rr)
#pragma unroll
                for (int i = 0; i < 8; ++i)
                    acc[rr] = fmaf(wr[rr][k + i], hv[i], acc[rr]);
        }
        if (layer == 0 && wv == 0) {        // ragged f=512 tail
            float hv = inA[(size_t)512 * BB + lane];
#pragma unroll
            for (int rr = 0; rr < 8; ++rr)
                acc[rr] = fmaf(WA[(size_t)jr[rr] * FF + 512], hv, acc[rr]);
        }
    }
    // ---- phase B: own recurrence ----
    {
        const float* wr[8];
#pragma unroll
        for (int rr = 0; rr < 8; ++rr) wr[rr] = WB + (size_t)jr[rr] * HH + k0;
        const float* ip = inB + (size_t)k0 * BB + lane;
        for (int k = 0; k < 128; k += 8) {
            float hv[8];
#pragma unroll
            for (int i = 0; i < 8; ++i) hv[i] = ip[(size_t)(k + i) * BB];
#pragma unroll
            for (int rr = 0; rr < 8; ++rr)
#pragma unroll
                for (int i = 0; i < 8; ++i)
                    acc[rr] = fmaf(wr[rr][k + i], hv[i], acc[rr]);
        }
    }

    __shared__ float part[4][8][64];
#pragma unroll
    for (int rr = 0; rr < 8; ++rr) part[wv][rr][lane] = acc[rr];
    __syncthreads();

    if (tid < 128) {
        const int ui = tid >> 6, b = lane;
        const int u = u0 + ui;
        float g[4];
#pragma unroll
        for (int gi = 0; gi < 4; ++gi) {
            float v = part[0][gi * 2 + ui][b] + part[1][gi * 2 + ui][b]
                    + part[2][gi * 2 + ui][b] + part[3][gi * 2 + ui][b];
            g[gi] = v + bihp[gi * HH + u] + bhhp[gi * HH + u];
        }
        float cold = cst[(size_t)u * BB + b];
        float cn = sigf(g[1]) * cold + sigf(g[0]) * tanhf(g[2]);
        float hn = sigf(g[3]) * tanhf(cn);
        cst[(size_t)u * BB + b] = cn;
        hout[(size_t)u * BB + b] = hn;
    }
}

// ---------------- final FCs ----------------
template <bool RELU, bool TOUT>
__global__ __launch_bounds__(256) void linear_T(
    const float* __restrict__ inT,   // [K][64]
    const float* __restrict__ W,     // [N][K]
    const float* __restrict__ bias,
    float* __restrict__ out,         // TOUT: [N][64] else [64][N]
    int N, int K)
{
    const int lane = (int)threadIdx.x & 63;
    const int nl = __builtin_amdgcn_readfirstlane((int)threadIdx.x >> 6);
    const int n = (int)blockIdx.x * 4 + nl;
    if (n >= N) return;
    float acc = 0.f;
    for (int k = 0; k < K; k += 8) {
        float hv[8];
#pragma unroll
        for (int i = 0; i < 8; ++i) hv[i] = inT[(size_t)(k + i) * 64 + lane];
        const float* wr = W + (size_t)n * K + k;
#pragma unroll
        for (int i = 0; i < 8; ++i) acc = fmaf(wr[i], hv[i], acc);
    }
    acc += bias[n];
    if (RELU) acc = fmaxf(acc, 0.f);
    if (TOUT) out[(size_t)n * 64 + lane] = acc;
    else      out[(size_t)lane * N + n] = acc;
}

extern "C" void kernel_launch(void* const* d_in, const int* in_sizes, int n_in,
                              void* d_out, int out_size, void* d_ws, size_t ws_size,
                              hipStream_t stream)
{
    const float* x     = (const float*)d_in[0];
    const float* Wih1  = (const float*)d_in[1];
    const float* Whh1  = (const float*)d_in[2];
    const float* bih1  = (const float*)d_in[3];
    const float* bhh1  = (const float*)d_in[4];
    const float* Wih2  = (const float*)d_in[5];
    const float* Whh2  = (const float*)d_in[6];
    const float* bih2  = (const float*)d_in[7];
    const float* bhh2  = (const float*)d_in[8];
    const float* Wih3  = (const float*)d_in[9];
    const float* Whh3  = (const float*)d_in[10];
    const float* bih3  = (const float*)d_in[11];
    const float* bhh3  = (const float*)d_in[12];
    const float* fc1_w = (const float*)d_in[13];
    const float* fc1_b = (const float*)d_in[14];
    const float* fc2_w = (const float*)d_in[15];
    const float* fc2_b = (const float*)d_in[16];

    float* ws = (float*)d_ws;
    // layout (floats): xring[2][XCH/..] | Hst[3][2][SB] | Cst[3][SB] | hidT[SB]
    float* xring = ws;
    float* Hst   = xring + (size_t)2 * XCH;
    float* Cst   = Hst + 6 * (size_t)SB;
    float* hidT  = Cst + 3 * (size_t)SB;
    const size_t need = (size_t)2 * XCH + 10 * (size_t)SB;
    if (ws_size < need * sizeof(float)) return;

    // init states: h_l -> Hst[l][0], c_l -> Cst[l]
    transpose_states<<<768, 256, 0, stream>>>(
        (const float*)d_in[17], (const float*)d_in[18], (const float*)d_in[19],
        (const float*)d_in[20], (const float*)d_in[21], (const float*)d_in[22],
        Hst + 0 * (size_t)SB, Cst + 0 * (size_t)SB,
        Hst + 2 * (size_t)SB, Cst + 1 * (size_t)SB,
        Hst + 4 * (size_t)SB, Cst + 2 * (size_t)SB);

    for (int s = 0; s < TT + 2; ++s) {
        if (s < TT && (s & 63) == 0)
            transpose_xchunk<<<513, 256, 0, stream>>>(x, xring, s >> 6);
        lstm_diag<<<768, 256, 0, stream>>>(
            s, xring,
            Wih1, Whh1, bih1, bhh1,
            Wih2, Whh2, bih2, bhh2,
            Wih3, Whh3, bih3, bhh3,
            Hst, Cst);
    }

    // final h3 is in Hst[2][ (511+1)&1 = 0 ] = Hst + 4*SB
    linear_T<true,  true ><<<128, 256, 0, stream>>>(Hst + 4 * (size_t)SB, fc1_w, fc1_b, hidT, 512, 512);
    linear_T<false, false><<<129, 256, 0, stream>>>(hidT, fc2_w, fc2_b, (float*)d_out, 513, 512);
}

// Round 4
// 16695.015 us; speedup vs baseline: 11.4601x; 1.0581x over previous
//
#include <hip/hip_runtime.h>
#include <math.h>

// 3-layer LSTM (B=64,H=512,T=512,F=513) + FC(512)->ReLU->FC(513).
// R3: split-bf16 MFMA (3-product trick ~ fp32 accurate).
//  G^T[64][2048] = in^T[64][K] @ W^T[K][2048] via mfma_f32_16x16x32_bf16.
//  Weights prepacked to fragment-linear bf16 hi/lo blobs (gate-interleaved
//  rows j'=4u+g). h kept as bf16 hi/lo row-major [b][512]; x pre-split per
//  64-t chunk (single buffer, serialized by launch order).
//  Grid 96 = 3 layers x 16 jblk(128 j' cols) x 2 bblk(32 batch rows);
//  4-wave K-split; LDS partial reduce + fused LSTM pointwise epilogue.

#define BB 64
#define HH 512
#define TT 512
#define FF 513
#define KX 544                 // padded x-K (17 tiles of 32)
#define KT1 33                 // L1 blob k-tiles (17 x + 16 h)
#define KT23 32
#define SBH 32768              // shorts per h slot (64*512)
#define BLOB1 2162688          // 128*33*512
#define BLOB23 2097152         // 128*32*512
#define OFF2 2162688
#define OFF3 4259840
#define TOTB 6356992

typedef __attribute__((ext_vector_type(8))) short s16x8;
typedef __attribute__((ext_vector_type(4))) short s16x4;
typedef __attribute__((ext_vector_type(4))) float f32x4;

__device__ __forceinline__ float sigf(float x) { return 1.0f / (1.0f + expf(-x)); }

__device__ __forceinline__ float bf2f(short s) {
    return __uint_as_float(((unsigned)(unsigned short)s) << 16);
}
__device__ __forceinline__ short f2bf(float w) {   // RNE
    unsigned u = __float_as_uint(w);
    return (short)((u + 0x7fff + ((u >> 16) & 1)) >> 16);
}
__device__ __forceinline__ void bfsplit(float w, short& hi, short& lo) {
    hi = f2bf(w);
    lo = f2bf(w - bf2f(hi));
}
__device__ __forceinline__ s16x8 cat44(s16x4 a, s16x4 b) {
    s16x8 r;
    r[0]=a[0]; r[1]=a[1]; r[2]=a[2]; r[3]=a[3];
    r[4]=b[0]; r[5]=b[1]; r[6]=b[2]; r[7]=b[3];
    return r;
}

// ---------- prep: initial h -> bf16 hi/lo (same [b][u] layout) ----------
__global__ __launch_bounds__(256) void prep_state_h(
    const float* __restrict__ h1, const float* __restrict__ h2,
    const float* __restrict__ h3, short* __restrict__ Hh, short* __restrict__ Hl)
{
    int idx = blockIdx.x * 256 + threadIdx.x;          // 3*32768
    int l = idx >> 15, e = idx & 32767;
    const float* s = l == 0 ? h1 : l == 1 ? h2 : h3;
    short hi, lo; bfsplit(s[e], hi, lo);
    Hh[(size_t)(l * 2) * SBH + e] = hi;                 // slot 0
    Hl[(size_t)(l * 2) * SBH + e] = lo;
}

// ---------- prep: initial c transpose [b][u] -> cT[u][b] ----------
__global__ __launch_bounds__(256) void prep_state_c(
    const float* __restrict__ c1, const float* __restrict__ c2,
    const float* __restrict__ c3, float* __restrict__ cT)
{
    __shared__ float tile[64][65];
    int l = blockIdx.x >> 3, ut = blockIdx.x & 7;
    const float* s = l == 0 ? c1 : l == 1 ? c2 : c3;
    int u0 = ut * 64, tid = threadIdx.x;
#pragma unroll
    for (int p = 0; p < 16; ++p) {
        int b = p * 4 + (tid >> 6), u = tid & 63;
        tile[u][b] = s[(size_t)b * HH + u0 + u];
    }
    __syncthreads();
#pragma unroll
    for (int p = 0; p < 16; ++p) {
        int ul = p * 4 + (tid >> 6), b = tid & 63;
        cT[(size_t)l * (HH * BB) + (size_t)(u0 + ul) * BB + b] = tile[ul][b];
    }
}

// ---------- prep: bias sums, gate-interleaved ----------
__global__ __launch_bounds__(256) void prep_bias(
    const float* __restrict__ bi1, const float* __restrict__ bh1,
    const float* __restrict__ bi2, const float* __restrict__ bh2,
    const float* __restrict__ bi3, const float* __restrict__ bh3,
    float* __restrict__ bsum)
{
    int idx = blockIdx.x * 256 + threadIdx.x;          // 3*2048
    if (idx >= 6144) return;
    int l = idx >> 11, jq = idx & 2047;
    int u = jq >> 2, g = jq & 3;
    const float* bi = l == 0 ? bi1 : l == 1 ? bi2 : bi3;
    const float* bh = l == 0 ? bh1 : l == 1 ? bh2 : bh3;
    bsum[idx] = bi[g * HH + u] + bh[g * HH + u];
}

// ---------- prep: weight blobs (fragment-linear, split hi/lo) ----------
__global__ __launch_bounds__(256) void prep_blob(
    const float* __restrict__ Wih1, const float* __restrict__ Whh1,
    const float* __restrict__ Wih2, const float* __restrict__ Whh2,
    const float* __restrict__ Wih3, const float* __restrict__ Whh3,
    short* __restrict__ Bh, short* __restrict__ Bl)
{
    int idx = blockIdx.x * 256 + threadIdx.x;          // TOTB exact
    int l, e, KTl;
    if (idx < OFF2)      { l = 0; e = idx;        KTl = KT1;  }
    else if (idx < OFF3) { l = 1; e = idx - OFF2; KTl = KT23; }
    else                 { l = 2; e = idx - OFF3; KTl = KT23; }
    int jtkt = e >> 9, r = e & 511;
    int lane = r >> 3, i = r & 7;
    int jt = jtkt / KTl, kt = jtkt - jt * KTl;
    int n = lane & 15, g = (lane >> 4) & 3;
    int jq = jt * 16 + n;
    int u = jq >> 2, gate = jq & 3;
    int row = gate * HH + u;
    int kk = kt * 32 + ((i < 4) ? (g * 4 + i) : (16 + g * 4 + (i - 4)));
    float w;
    if (l == 0) {
        if (kk < KX) w = (kk < FF) ? Wih1[(size_t)row * FF + kk] : 0.f;
        else         w = Whh1[(size_t)row * HH + (kk - KX)];
    } else if (l == 1) {
        w = (kk < HH) ? Wih2[(size_t)row * HH + kk] : Whh2[(size_t)row * HH + kk - HH];
    } else {
        w = (kk < HH) ? Wih3[(size_t)row * HH + kk] : Whh3[(size_t)row * HH + kk - HH];
    }
    short hi, lo; bfsplit(w, hi, lo);
    Bh[idx] = hi; Bl[idx] = lo;
}

// ---------- prep: x chunk -> [tt][b][544] bf16 hi/lo ----------
__global__ __launch_bounds__(256) void prep_x(
    const float* __restrict__ x, short* __restrict__ Xh, short* __restrict__ Xl, int c)
{
    __shared__ float tile[64][65];
    int b = blockIdx.x / 9, fg = blockIdx.x - b * 9;
    int t0 = c * 64, tid = threadIdx.x;
#pragma unroll
    for (int p = 0; p < 16; ++p) {
        int idx = p * 256 + tid;
        int fl = idx >> 6, tt = idx & 63;
        int f = fg * 64 + fl;
        tile[fl][tt] = (f < FF) ? x[((size_t)b * FF + f) * TT + t0 + tt] : 0.f;
    }
    __syncthreads();
#pragma unroll
    for (int p = 0; p < 2; ++p) {
        int idx = p * 256 + tid;
        int fg8 = idx & 7, tt = idx >> 3;
        int k0 = fg * 64 + fg8 * 8;
        if (k0 < KX) {
            s16x8 vh, vl;
#pragma unroll
            for (int q = 0; q < 8; ++q) {
                short hi, lo; bfsplit(tile[fg8 * 8 + q][tt], hi, lo);
                vh[q] = hi; vl[q] = lo;
            }
            size_t off = ((size_t)tt * BB + b) * KX + k0;
            *(s16x8*)(Xh + off) = vh;
            *(s16x8*)(Xl + off) = vl;
        }
    }
}

// ---------- the diagonal MFMA super-step ----------
// grid 96: layer = bid>>5; jblk = (bid&31)>>1 (128 j' cols); bblk = bid&1 (32 b rows)
__global__ __launch_bounds__(256) void lstm_mfma(
    int s,
    const short* __restrict__ Xh, const short* __restrict__ Xl,
    short* __restrict__ Hh, short* __restrict__ Hl,
    const short* __restrict__ Bh, const short* __restrict__ Bl,
    const float* __restrict__ bsum, float* __restrict__ cT)
{
    const int layer = (int)blockIdx.x >> 5;
    const int t = s - layer;
    if (t < 0 || t >= TT) return;
    const int rem = (int)blockIdx.x & 31;
    const int jblk = rem >> 1, bblk = rem & 1;
    const int tid = (int)threadIdx.x;
    const int lane = tid & 63;
    const int wv = __builtin_amdgcn_readfirstlane(tid >> 6);

    const int rl = lane & 15, g = lane >> 4;
    const int jtG0 = jblk * 8, u0 = jblk * 32;

    // per-wave K-split parameters
    const short *Ah, *Al;
    int lda, kb0, ktn, ktG0, KTl; size_t blobOff;
    if (layer == 0) {
        KTl = KT1; blobOff = 0;
        if (wv < 2) {
            size_t aB = (size_t)(t & 63) * (BB * KX);
            Ah = Xh + aB; Al = Xl + aB; lda = KX;
            kb0 = (wv == 0) ? 0 : 288; ktn = (wv == 0) ? 9 : 8; ktG0 = (wv == 0) ? 0 : 9;
        } else {
            size_t aB = (size_t)(0 * 2 + (t & 1)) * SBH;
            Ah = Hh + aB; Al = Hl + aB; lda = HH;
            kb0 = (wv == 2) ? 0 : 256; ktn = 8; ktG0 = (wv == 2) ? 17 : 25;
        }
    } else {
        KTl = KT23; blobOff = (layer == 1) ? OFF2 : OFF3;
        if (wv < 2) {
            size_t aB = (size_t)((layer - 1) * 2 + ((t + 1) & 1)) * SBH;
            Ah = Hh + aB; Al = Hl + aB;
            kb0 = wv * 256; ktn = 8; ktG0 = wv * 8;
        } else {
            size_t aB = (size_t)(layer * 2 + (t & 1)) * SBH;
            Ah = Hh + aB; Al = Hl + aB;
            kb0 = (wv - 2) * 256; ktn = 8; ktG0 = 16 + (wv - 2) * 8;
        }
        lda = HH;
    }

    const int rowBase = bblk * 32;
    const short* aPH = Ah + (size_t)(rowBase + rl) * lda + kb0 + g * 4;
    const short* aPL = Al + (size_t)(rowBase + rl) * lda + kb0 + g * 4;
    const short* bPH = Bh + blobOff + ((size_t)jtG0 * KTl + ktG0) * 512 + lane * 8;
    const short* bPL = Bl + blobOff + ((size_t)jtG0 * KTl + ktG0) * 512 + lane * 8;

    f32x4 acc[8][2];
#pragma unroll
    for (int jj = 0; jj < 8; ++jj)
#pragma unroll
        for (int bt = 0; bt < 2; ++bt) acc[jj][bt] = (f32x4){0.f, 0.f, 0.f, 0.f};

    for (int it = 0; it < ktn; ++it) {
        s16x8 aH[2], aL[2];
#pragma unroll
        for (int bt = 0; bt < 2; ++bt) {
            const short* p = aPH + it * 32 + (size_t)(bt * 16) * lda;
            aH[bt] = cat44(*(const s16x4*)p, *(const s16x4*)(p + 16));
            const short* q = aPL + it * 32 + (size_t)(bt * 16) * lda;
            aL[bt] = cat44(*(const s16x4*)q, *(const s16x4*)(q + 16));
        }
#pragma unroll
        for (int jj = 0; jj < 8; ++jj) {
            s16x8 bH = *(const s16x8*)(bPH + ((size_t)jj * KTl + it) * 512);
            s16x8 bL = *(const s16x8*)(bPL + ((size_t)jj * KTl + it) * 512);
#pragma unroll
            for (int bt = 0; bt < 2; ++bt) {
                acc[jj][bt] = __builtin_amdgcn_mfma_f32_16x16x32_bf16(aH[bt], bH, acc[jj][bt], 0, 0, 0);
                acc[jj][bt] = __builtin_amdgcn_mfma_f32_16x16x32_bf16(aL[bt], bH, acc[jj][bt], 0, 0, 0);
                acc[jj][bt] = __builtin_amdgcn_mfma_f32_16x16x32_bf16(aH[bt], bL, acc[jj][bt], 0, 0, 0);
            }
        }
    }

    // partials: P[w][jl 0..127][bl 0..31] (pad 33)
    __shared__ float Pf[4 * 128 * 33];
    __shared__ short hstH[32 * 40];
    __shared__ short hstL[32 * 40];
#pragma unroll
    for (int jj = 0; jj < 8; ++jj)
#pragma unroll
        for (int bt = 0; bt < 2; ++bt)
#pragma unroll
            for (int r = 0; r < 4; ++r)
                Pf[(wv * 128 + jj * 16 + rl) * 33 + bt * 16 + g * 4 + r] = acc[jj][bt][r];
    __syncthreads();

    {   // reduce + pointwise: thread = (bl = tid&31, ul = tid>>5)
        const int bl = tid & 31, ul = tid >> 5;
        const int bg = bblk * 32 + bl;
        const int slotOut = (t + 1) & 1;
#pragma unroll
        for (int sgrp = 0; sgrp < 4; ++sgrp) {
            const int lu = ul + sgrp * 8;
            const int u = u0 + lu;
            float G[4];
#pragma unroll
            for (int gi = 0; gi < 4; ++gi) {
                const int jl = lu * 4 + gi;
                float v = Pf[(0 * 128 + jl) * 33 + bl] + Pf[(1 * 128 + jl) * 33 + bl]
                        + Pf[(2 * 128 + jl) * 33 + bl] + Pf[(3 * 128 + jl) * 33 + bl];
                G[gi] = v + bsum[layer * 2048 + jblk * 128 + jl];
            }
            float* cp = cT + (size_t)layer * (HH * BB) + (size_t)u * BB + bg;
            float cold = *cp;
            float cn = sigf(G[1]) * cold + sigf(G[0]) * tanhf(G[2]);
            float hn = sigf(G[3]) * tanhf(cn);
            *cp = cn;
            short hi, lo; bfsplit(hn, hi, lo);
            hstH[bl * 40 + lu] = hi;
            hstL[bl * 40 + lu] = lo;
        }
        __syncthreads();
        if (tid < 128) {
            const int brow = tid >> 2, seg = tid & 3;
            s16x8 vh = *(const s16x8*)(hstH + brow * 40 + seg * 8);
            s16x8 vl = *(const s16x8*)(hstL + brow * 40 + seg * 8);
            size_t off = (size_t)(layer * 2 + slotOut) * SBH
                       + (size_t)(bblk * 32 + brow) * HH + u0 + seg * 8;
            *(s16x8*)(Hh + off) = vh;
            *(s16x8*)(Hl + off) = vl;
        }
    }
}

// ---------- final FCs ----------
__global__ __launch_bounds__(256) void fc1_k(
    const short* __restrict__ H3h, const short* __restrict__ H3l,
    const float* __restrict__ W, const float* __restrict__ bias,
    float* __restrict__ hid)
{
    const int lane = (int)threadIdx.x & 63;                  // = b
    const int wv = __builtin_amdgcn_readfirstlane((int)threadIdx.x >> 6);
    const int n = (int)blockIdx.x * 4 + wv;                  // 0..511
    float acc = 0.f;
    const float* wr = W + (size_t)n * HH;
    for (int k = 0; k < HH; k += 8) {
        s16x8 vh = *(const s16x8*)(H3h + (size_t)lane * HH + k);
        s16x8 vl = *(const s16x8*)(H3l + (size_t)lane * HH + k);
#pragma unroll
        for (int i = 0; i < 8; ++i)
            acc = fmaf(bf2f(vh[i]) + bf2f(vl[i]), wr[k + i], acc);
    }
    acc += bias[n];
    hid[(size_t)lane * HH + n] = fmaxf(acc, 0.f);
}

__global__ __launch_bounds__(256) void fc2_k(
    const float* __restrict__ hid, const float* __restrict__ W,
    const float* __restrict__ bias, float* __restrict__ out)
{
    const int lane = (int)threadIdx.x & 63;                  // = b
    const int wv = __builtin_amdgcn_readfirstlane((int)threadIdx.x >> 6);
    const int n = (int)blockIdx.x * 4 + wv;                  // 0..515
    if (n >= FF) return;
    float acc = 0.f;
    const float* wr = W + (size_t)n * HH;
    const float* hp = hid + (size_t)lane * HH;
    for (int k = 0; k < HH; k += 8) {
        float4 a = *(const float4*)(hp + k);
        float4 b = *(const float4*)(hp + k + 4);
        acc = fmaf(a.x, wr[k+0], acc); acc = fmaf(a.y, wr[k+1], acc);
        acc = fmaf(a.z, wr[k+2], acc); acc = fmaf(a.w, wr[k+3], acc);
        acc = fmaf(b.x, wr[k+4], acc); acc = fmaf(b.y, wr[k+5], acc);
        acc = fmaf(b.z, wr[k+6], acc); acc = fmaf(b.w, wr[k+7], acc);
    }
    out[(size_t)lane * FF + n] = acc + bias[n];
}

extern "C" void kernel_launch(void* const* d_in, const int* in_sizes, int n_in,
                              void* d_out, int out_size, void* d_ws, size_t ws_size,
                              hipStream_t stream)
{
    const float* x     = (const float*)d_in[0];
    const float* Wih1  = (const float*)d_in[1];
    const float* Whh1  = (const float*)d_in[2];
    const float* bih1  = (const float*)d_in[3];
    const float* bhh1  = (const float*)d_in[4];
    const float* Wih2  = (const float*)d_in[5];
    const float* Whh2  = (const float*)d_in[6];
    const float* bih2  = (const float*)d_in[7];
    const float* bhh2  = (const float*)d_in[8];
    const float* Wih3  = (const float*)d_in[9];
    const float* Whh3  = (const float*)d_in[10];
    const float* bih3  = (const float*)d_in[11];
    const float* bhh3  = (const float*)d_in[12];
    const float* fc1_w = (const float*)d_in[13];
    const float* fc1_b = (const float*)d_in[14];
    const float* fc2_w = (const float*)d_in[15];
    const float* fc2_b = (const float*)d_in[16];

    char* p = (char*)d_ws;
    float* cT   = (float*)p;            p += (size_t)3 * HH * BB * 4;      // 393216
    float* hid  = (float*)p;            p += (size_t)HH * BB * 4;          // 131072
    float* bsum = (float*)p;            p += 6144 * 4;                     // 24576
    short* HBFh = (short*)p;            p += (size_t)6 * SBH * 2;          // 393216
    short* HBFl = (short*)p;            p += (size_t)6 * SBH * 2;
    short* XBFh = (short*)p;            p += (size_t)BB * BB * KX * 2;     // 4456448
    short* XBFl = (short*)p;            p += (size_t)BB * BB * KX * 2;
    short* BLOBh = (short*)p;           p += (size_t)TOTB * 2;             // 12713984
    short* BLOBl = (short*)p;           p += (size_t)TOTB * 2;
    if ((size_t)(p - (char*)d_ws) > ws_size) return;

    prep_state_h<<<384, 256, 0, stream>>>(
        (const float*)d_in[17], (const float*)d_in[19], (const float*)d_in[21],
        HBFh, HBFl);
    prep_state_c<<<24, 256, 0, stream>>>(
        (const float*)d_in[18], (const float*)d_in[20], (const float*)d_in[22], cT);
    prep_bias<<<24, 256, 0, stream>>>(bih1, bhh1, bih2, bhh2, bih3, bhh3, bsum);
    prep_blob<<<TOTB / 256, 256, 0, stream>>>(Wih1, Whh1, Wih2, Whh2, Wih3, Whh3,
                                              BLOBh, BLOBl);

    for (int s = 0; s < TT + 2; ++s) {
        if (s < TT && (s & 63) == 0)
            prep_x<<<576, 256, 0, stream>>>(x, XBFh, XBFl, s >> 6);
        lstm_mfma<<<96, 256, 0, stream>>>(s, XBFh, XBFl, HBFh, HBFl,
                                          BLOBh, BLOBl, bsum, cT);
    }

    // final h3 @ t=511 -> slot (511+1)&1 = 0
    fc1_k<<<128, 256, 0, stream>>>(HBFh + (size_t)4 * SBH, HBFl + (size_t)4 * SBH,
                                   fc1_w, fc1_b, hid);
    fc2_k<<<129, 256, 0, stream>>>(hid, fc2_w, fc2_b, (float*)d_out);
}